// Round 14
// baseline (146.063 us; speedup 1.0000x reference)
//
#include <hip/hip_runtime.h>
#include <stdint.h>

#define D_MODEL 1024
#define NH 16
#define DKK 64
#define SEQ 2048
// softmax scale folded into Q projection: 0.125 * log2(e)
#define QSCALE 0.18033688011112042f

using half8 = __attribute__((ext_vector_type(8))) _Float16;
using half4 = __attribute__((ext_vector_type(4))) _Float16;
using half2v = __attribute__((ext_vector_type(2))) _Float16;
using fp16x2 = __attribute__((ext_vector_type(2))) __fp16;
using f32x4 = __attribute__((ext_vector_type(4))) float;
using f32x16 = __attribute__((ext_vector_type(16))) float;

__device__ __forceinline__ f32x4 fz4() { f32x4 v = {0.f, 0.f, 0.f, 0.f}; return v; }

// async global->LDS, 16B per lane; LDS dest = wave-uniform base + lane*16
__device__ __forceinline__ void gload16(const void* g, void* l) {
    __builtin_amdgcn_global_load_lds(
        (const __attribute__((address_space(1))) unsigned int*)g,
        (__attribute__((address_space(3))) unsigned int*)l, 16, 0, 0);
}

__device__ __forceinline__ half2v pk2(float a, float b) {
    fp16x2 t = __builtin_amdgcn_cvt_pkrtz(a, b);
    return __builtin_bit_cast(half2v, t);
}

__device__ __forceinline__ half4 pk4(float a, float b, float c, float d) {
    half2v lo = pk2(a, b);
    half2v hi = pk2(c, d);
    half4 r; r.x = lo.x; r.y = lo.y; r.z = hi.x; r.w = hi.y;
    return r;
}

// XCD-chunked swizzle
__device__ __forceinline__ int xswz(int bid, int n) {
    return (bid & 7) * (n >> 3) + (bid >> 3);
}

// ---------------- fused prep: fp32->fp16 [W|Q|K|V] + mask bitpack ----------------
__global__ __launch_bounds__(256) void prep(const float* __restrict__ wq,
                                            const float* __restrict__ wk,
                                            const float* __restrict__ wv,
                                            const float* __restrict__ wo,
                                            const float* __restrict__ Q,
                                            const float* __restrict__ K,
                                            const float* __restrict__ V,
                                            const int* __restrict__ mask,
                                            _Float16* __restrict__ out,
                                            unsigned int* __restrict__ mbits) {
    const int bid = blockIdx.x;
    if (bid < 2048) {
        int idx = bid * 256 + threadIdx.x;
#pragma unroll
        for (int k = 0; k < 8; ++k) {
            int c = idx + k * 524288;
            const float* src;
            int off;
            if (c < 1048576) {
                int w = c >> 18;
                src = (w == 0) ? wq : (w == 1) ? wk : (w == 2) ? wv : wo;
                off = c & 0x3ffff;
            } else {
                int j = (c >> 20) - 1;
                src = (j == 0) ? Q : (j == 1) ? K : V;
                off = c & 0xfffff;
            }
            float4 v = ((const float4*)src)[off];
            ((half4*)out)[c] = pk4(v.x, v.y, v.z, v.w);
        }
    } else {
        int wid = threadIdx.x >> 6, lane = threadIdx.x & 63;
        int row = (bid - 2048) * 4 + wid;
        const int* mrow = mask + (size_t)row * SEQ;
        unsigned int* orow = mbits + (size_t)row * (SEQ / 32);
        for (int it = 0; it < SEQ / 64; ++it) {
            int v = mrow[it * 64 + lane];
            unsigned long long bal = __ballot(v != 0);
            if (lane == 0)       orow[it * 2]     = (unsigned int)(bal & 0xffffffffull);
            else if (lane == 32) orow[it * 2 + 1] = (unsigned int)(bal >> 32);
        }
    }
}

// ---------------- GEMM body: counted-vmcnt 2-barrier pipeline ----------------
__device__ __forceinline__ void gemm_body(const _Float16* __restrict__ A,
                                          const _Float16* __restrict__ Wh,
                                          const float* __restrict__ bias,
                                          void* __restrict__ outp, int omode, float scale) {
    __shared__ __align__(16) _Float16 Asm[2][64 * 64];
    __shared__ __align__(16) _Float16 Bsm[2][128 * 64];
    const int tid = threadIdx.x;
    const int wg = xswz(blockIdx.x, 512);
    const int bm = wg >> 3, bn = wg & 7;
    const int wid = tid >> 6, lane = tid & 63;
    const int li = lane & 15, g = lane >> 4;
    const int wm = wid >> 1, wn = wid & 1;

    const int brow = wid * 32 + (lane >> 3);
    const char* bsrc = (const char*)(Wh + (size_t)(bn * 128 + brow) * D_MODEL)
                       + (((lane & 7) ^ (brow & 7)) * 16);
    const int bdst = wid * 32 * 128;
    const int arow = wid * 16 + (lane >> 3);
    const char* asrc = (const char*)(A + (size_t)(bm * 64 + arow) * D_MODEL)
                       + (((lane & 7) ^ (arow & 7)) * 16);
    const int adst = wid * 16 * 128;

    f32x4 acc[2][4];
#pragma unroll
    for (int i = 0; i < 2; ++i)
#pragma unroll
        for (int j = 0; j < 4; ++j) acc[i][j] = fz4();

    const int o0 = ((g << 4))      ^ ((li & 7) << 4);
    const int o1 = (64 + (g << 4)) ^ ((li & 7) << 4);
    const int abase = wm * 4096 + li * 128;
    const int bbase = wn * 8192 + li * 128;

    auto stage = [&](int it, int buf) {
        const char* bs = bsrc + it * 128;
        char* bd = (char*)&Bsm[buf][0] + bdst;
        gload16(bs,             bd);
        gload16(bs +  8 * 2048, bd + 1024);
        gload16(bs + 16 * 2048, bd + 2048);
        gload16(bs + 24 * 2048, bd + 3072);
        const char* as = asrc + it * 128;
        char* ad = (char*)&Asm[buf][0] + adst;
        gload16(as,            ad);
        gload16(as + 8 * 2048, ad + 1024);
    };

    stage(0, 0);

    for (int it = 0; it < 16; ++it) {
        const int cur = it & 1;
        if (it + 1 < 16) {
            stage(it + 1, cur ^ 1);
            asm volatile("s_waitcnt vmcnt(6)" ::: "memory");   // tile-it loads landed; it+1 in flight
        } else {
            asm volatile("s_waitcnt vmcnt(0)" ::: "memory");
        }
        __builtin_amdgcn_s_barrier();                          // no drain: prefetch stays in flight
        __builtin_amdgcn_sched_barrier(0);
        const char* ab = (const char*)&Asm[cur][0];
        const char* bb = (const char*)&Bsm[cur][0];
#pragma unroll
        for (int s = 0; s < 2; ++s) {
            const int oS = s ? o1 : o0;
            half8 af0 = *(const half8*)(ab + abase + 0    + oS);
            half8 af1 = *(const half8*)(ab + abase + 2048 + oS);
            half8 bf[4];
#pragma unroll
            for (int nt = 0; nt < 4; ++nt)
                bf[nt] = *(const half8*)(bb + bbase + nt * 2048 + oS);
#pragma unroll
            for (int nt = 0; nt < 4; ++nt) {
                acc[0][nt] = __builtin_amdgcn_mfma_f32_16x16x32_f16(af0, bf[nt], acc[0][nt], 0, 0, 0);
                acc[1][nt] = __builtin_amdgcn_mfma_f32_16x16x32_f16(af1, bf[nt], acc[1][nt], 0, 0, 0);
            }
        }
        __builtin_amdgcn_sched_barrier(0);
        __builtin_amdgcn_s_barrier();                          // WAR: all read cur before it+2 staging
    }

#pragma unroll
    for (int nt = 0; nt < 4; ++nt) {
        int n = bn * 128 + wn * 64 + nt * 16 + li;
        float bv = bias[n];
#pragma unroll
        for (int mt = 0; mt < 2; ++mt) {
            if (omode == 1) {
                int s0 = bm * 64 + wm * 32 + mt * 16 + g * 4;
                int b = (bm * 64) >> 11;
                int h = n >> 6, d = n & 63;
                half4 hv = pk4(acc[mt][nt][0] + bv, acc[mt][nt][1] + bv,
                               acc[mt][nt][2] + bv, acc[mt][nt][3] + bv);
                *(half4*)((_Float16*)outp +
                          ((((size_t)(b * NH + h)) * DKK + d) * SEQ + (s0 & (SEQ - 1)))) = hv;
            } else {
#pragma unroll
                for (int r = 0; r < 4; ++r) {
                    int m = bm * 64 + wm * 32 + mt * 16 + g * 4 + r;
                    float val = (acc[mt][nt][r] + bv) * scale;
                    if (omode == 2) {
                        ((float*)outp)[(size_t)m * D_MODEL + n] = val;
                    } else {
                        int b = m >> 11, s = m & (SEQ - 1);
                        int h = n >> 6, d = n & 63;
                        ((_Float16*)outp)[(((size_t)(b * NH + h)) * SEQ + s) * DKK + d] =
                            (_Float16)val;
                    }
                }
            }
        }
    }
}

struct QkvArgs {
    const float *b0, *b1, *b2;
    _Float16 *o0, *o1, *o2;
};

__global__ __launch_bounds__(256) void gemm_qkv(const _Float16* __restrict__ Ah,
                                                const _Float16* __restrict__ cw,
                                                QkvArgs ga) {
    const int z = blockIdx.y;
    const _Float16* A  = Ah + (size_t)z * (D_MODEL * 4096);
    const float* bi = (z == 0) ? ga.b0 : (z == 1) ? ga.b1 : ga.b2;
    _Float16*    o  = (z == 0) ? ga.o0 : (z == 1) ? ga.o1 : ga.o2;
    gemm_body(A, cw + (size_t)z * D_MODEL * D_MODEL, bi, o,
              (z == 2) ? 1 : 0, (z == 0) ? QSCALE : 1.0f);
}

__global__ __launch_bounds__(256) void gemm_out(const _Float16* __restrict__ A,
                                                const _Float16* __restrict__ cw,
                                                const float* __restrict__ bias,
                                                float* __restrict__ out) {
    gemm_body(A, cw, bias, out, 2, 1.0f);
}

// ---------------- attention: 32x32 MFMA, in-reg P, ones-MFMA lsum, counted-vmcnt ----------------
__global__ __launch_bounds__(256, 4) void attn_fwd(const _Float16* __restrict__ q,
                                                   const _Float16* __restrict__ kk,
                                                   const _Float16* __restrict__ vt,
                                                   const unsigned int* __restrict__ mb,
                                                   _Float16* __restrict__ aout) {
    __shared__ __align__(16) char smem[32768];
    const int wg = xswz(blockIdx.x, 1024);
    const int qblk = wg & 31, bh = wg >> 5;
    const int b = bh >> 4, h = bh & 15;
    const int tid = threadIdx.x, wid = tid >> 6, lane = tid & 63;
    const int l31 = lane & 31, hi = lane >> 5;
    const int qh = wid & 1, kh = wid >> 1;     // wave -> (q-half, key-half)
    const _Float16* qp = q  + (size_t)bh * SEQ * DKK;
    const _Float16* kp = kk + (size_t)bh * SEQ * DKK;
    const _Float16* vp = vt + (size_t)bh * DKK * SEQ;
    const int qrow = qblk * 64 + qh * 32 + l31;

    half8 qf[4];
#pragma unroll
    for (int s = 0; s < 4; ++s)
        qf[s] = *(const half8*)(qp + (size_t)qrow * DKK + s * 16 + hi * 8);

    half8 ones;
#pragma unroll
    for (int j = 0; j < 8; ++j) ones[j] = (_Float16)1.0f;

    const int srow = wid * 16 + (lane >> 3);
    const int sswz = ((lane & 7) ^ (srow & 7)) * 16;
    const char* ksrc = (const char*)(kp + (size_t)srow * DKK) + sswz;
    const char* vsrc = (const char*)(vp + (size_t)srow * SEQ) + sswz;
    const int sdst = wid * 2048;

    auto stage = [&](int it, int buf) {
        const char* ks = ksrc + (size_t)it * 8192;
        const char* vs = vsrc + (size_t)it * 128;
        char* kd = smem + buf * 8192 + sdst;
        char* vd = smem + 16384 + buf * 8192 + sdst;
        gload16(ks,                       kd);
        gload16(ks + 8 * 128,             kd + 1024);
        gload16(vs,                       vd);
        gload16(vs + 8 * (size_t)SEQ * 2, vd + 1024);
    };

    f32x16 O0, O1, Ol;
#pragma unroll
    for (int j = 0; j < 16; ++j) { O0[j] = 0.f; O1[j] = 0.f; Ol[j] = 0.f; }

    const unsigned int* mrow = mb + (size_t)(b * SEQ + qrow) * (SEQ / 32);

    const int krow = kh * 32 + l31;
    const int kbase = krow * 128;
    const int krx = (krow & 7);
    const int v0row = l31;
    const int v1row = 32 + l31;

    stage(0, 0);

    for (int it = 0; it < SEQ / 64; ++it) {
        const int cur = it & 1;
        const unsigned mw = mrow[it * 2 + kh] >> (hi * 4);   // issued before stage
        if (it + 1 < SEQ / 64) {
            stage(it + 1, cur ^ 1);
            asm volatile("s_waitcnt vmcnt(4)" ::: "memory"); // tile-it landed; it+1 in flight
        } else {
            asm volatile("s_waitcnt vmcnt(0)" ::: "memory");
        }
        __builtin_amdgcn_s_barrier();                        // no drain
        __builtin_amdgcn_sched_barrier(0);

        f32x16 st;
#pragma unroll
        for (int j = 0; j < 16; ++j) st[j] = 0.f;
        const char* kb_ = smem + cur * 8192;
        __builtin_amdgcn_s_setprio(1);
#pragma unroll
        for (int s = 0; s < 4; ++s) {
            const int c = s * 2 + hi;
            half8 kf = *(const half8*)(kb_ + kbase + ((c ^ krx) << 4));
            st = __builtin_amdgcn_mfma_f32_32x32x16_f16(kf, qf[s], st, 0, 0, 0);
        }
        __builtin_amdgcn_s_setprio(0);

        unsigned w[8];
#pragma unroll
        for (int rq = 0; rq < 4; ++rq) {
            float e0 = __builtin_amdgcn_exp2f(st[rq * 4 + 0]);
            float e1 = __builtin_amdgcn_exp2f(st[rq * 4 + 1]);
            float e2 = __builtin_amdgcn_exp2f(st[rq * 4 + 2]);
            float e3 = __builtin_amdgcn_exp2f(st[rq * 4 + 3]);
            float p0 = ((mw >> (8 * rq + 0)) & 1u) ? e0 : 1.0f;
            float p1 = ((mw >> (8 * rq + 1)) & 1u) ? e1 : 1.0f;
            float p2 = ((mw >> (8 * rq + 2)) & 1u) ? e2 : 1.0f;
            float p3 = ((mw >> (8 * rq + 3)) & 1u) ? e3 : 1.0f;
            w[2 * rq]     = __builtin_bit_cast(unsigned, pk2(p0, p1));
            w[2 * rq + 1] = __builtin_bit_cast(unsigned, pk2(p2, p3));
        }

        half8 pfrag[2];
#pragma unroll
        for (int s2 = 0; s2 < 2; ++s2) {
            unsigned a0 = w[s2 * 4 + 0], a1 = w[s2 * 4 + 1];
            unsigned a2 = w[s2 * 4 + 2], a3 = w[s2 * 4 + 3];
            unsigned t0 = (unsigned)__shfl_xor((int)(hi ? a0 : a2), 32);
            unsigned t1 = (unsigned)__shfl_xor((int)(hi ? a1 : a3), 32);
            uint4 f;
            f.x = hi ? t0 : a0;
            f.y = hi ? t1 : a1;
            f.z = hi ? a2 : t0;
            f.w = hi ? a3 : t1;
            pfrag[s2] = __builtin_bit_cast(half8, f);
        }

        const char* vb_ = smem + 16384 + cur * 8192;
        __builtin_amdgcn_s_setprio(1);
#pragma unroll
        for (int s2 = 0; s2 < 2; ++s2) {
            const int c = kh * 4 + s2 * 2 + hi;
            half8 vf0 = *(const half8*)(vb_ + v0row * 128 + ((c ^ (v0row & 7)) << 4));
            half8 vf1 = *(const half8*)(vb_ + v1row * 128 + ((c ^ (v1row & 7)) << 4));
            Ol = __builtin_amdgcn_mfma_f32_32x32x16_f16(ones, pfrag[s2], Ol, 0, 0, 0);
            O0 = __builtin_amdgcn_mfma_f32_32x32x16_f16(vf0, pfrag[s2], O0, 0, 0, 0);
            O1 = __builtin_amdgcn_mfma_f32_32x32x16_f16(vf1, pfrag[s2], O1, 0, 0, 0);
        }
        __builtin_amdgcn_s_setprio(0);
        __builtin_amdgcn_sched_barrier(0);
        __builtin_amdgcn_s_barrier();                        // WAR: all read cur before it+2 staging
    }

    // ---- epilogue: combine key-halves; lsum = Ol[0] ----
    float lsum = Ol[0];

    const int SSTR = 36;
    float* scr = (float*)smem;
    float* lscr = (float*)(smem + 2 * 64 * SSTR * 4);
    if (kh == 1) {
        float* dst = scr + (size_t)qh * (64 * SSTR) + lane * SSTR;
#pragma unroll
        for (int j = 0; j < 4; ++j) {
            *(f32x4*)(dst + j * 4)      = *((f32x4*)&O0 + j);
            *(f32x4*)(dst + 16 + j * 4) = *((f32x4*)&O1 + j);
        }
        if (hi == 0) lscr[qh * 32 + l31] = lsum;
    }
    __syncthreads();
    if (kh == 0) {
        const float* src = scr + (size_t)qh * (64 * SSTR) + lane * SSTR;
#pragma unroll
        for (int j = 0; j < 16; ++j) { O0[j] += src[j]; O1[j] += src[16 + j]; }
        float inv = 1.0f / (lsum + lscr[qh * 32 + l31]);
        _Float16* orow = aout + ((size_t)(b * SEQ + qrow)) * D_MODEL + h * DKK + hi * 4;
#pragma unroll
        for (int rq = 0; rq < 4; ++rq) {
            *(half4*)(orow + 8 * rq) =
                pk4(O0[rq * 4 + 0] * inv, O0[rq * 4 + 1] * inv,
                    O0[rq * 4 + 2] * inv, O0[rq * 4 + 3] * inv);
            *(half4*)(orow + 32 + 8 * rq) =
                pk4(O1[rq * 4 + 0] * inv, O1[rq * 4 + 1] * inv,
                    O1[rq * 4 + 2] * inv, O1[rq * 4 + 3] * inv);
        }
    }
}

extern "C" void kernel_launch(void* const* d_in, const int* in_sizes, int n_in,
                              void* d_out, int out_size, void* d_ws, size_t ws_size,
                              hipStream_t stream) {
    const float* Q    = (const float*)d_in[0];
    const float* Kin  = (const float*)d_in[1];
    const float* Vin  = (const float*)d_in[2];
    const int*   mask = (const int*)d_in[3];
    const float* WQw = (const float*)d_in[4];
    const float* WQb = (const float*)d_in[5];
    const float* WKw = (const float*)d_in[6];
    const float* WKb = (const float*)d_in[7];
    const float* WVw = (const float*)d_in[8];
    const float* WVb = (const float*)d_in[9];
    const float* WOw = (const float*)d_in[10];
    const float* WOb = (const float*)d_in[11];

    char* w = (char*)d_ws;
    const size_t MB = 1ull << 20;
    // ws layout (57 MB):
    //  [0,8)   cw    fp16 weights WQ|WK|WV|WO
    //  [8,32)  Ah    fp16 Q|K|V inputs (Q region [8,16) reused as ab after gemm_qkv)
    //  [32,40) qb  [40,48) kbf  [48,56) vtb
    //  [56,57) mbits
    _Float16* cw  = (_Float16*)(w);
    _Float16* Ah  = (_Float16*)(w + 8 * MB);
    _Float16* ab  = (_Float16*)(w + 8 * MB);
    _Float16* qb  = (_Float16*)(w + 32 * MB);
    _Float16* kbf = (_Float16*)(w + 40 * MB);
    _Float16* vtb = (_Float16*)(w + 48 * MB);
    unsigned int* mbits = (unsigned int*)(w + 56 * MB);

    prep<<<dim3(3072), dim3(256), 0, stream>>>(WQw, WKw, WVw, WOw, Q, Kin, Vin, mask,
                                               cw, mbits);

    QkvArgs ga;
    ga.b0 = WQb; ga.b1 = WKb; ga.b2 = WVb;
    ga.o0 = qb;  ga.o1 = kbf; ga.o2 = vtb;
    gemm_qkv<<<dim3(512, 3), dim3(256), 0, stream>>>(Ah, cw, ga);

    attn_fwd<<<dim3(1024), dim3(256), 0, stream>>>(qb, kbf, vtb, mbits, ab);

    gemm_out<<<dim3(512), dim3(256), 0, stream>>>(ab, cw + 3ull * D_MODEL * D_MODEL, WOb,
                                                  (float*)d_out);
}

// Round 15
// 141.150 us; speedup vs baseline: 1.0348x; 1.0348x over previous
//
#include <hip/hip_runtime.h>
#include <stdint.h>

#define D_MODEL 1024
#define NH 16
#define DKK 64
#define SEQ 2048
// softmax scale folded into Q projection: 0.125 * log2(e)
#define QSCALE 0.18033688011112042f

using half8 = __attribute__((ext_vector_type(8))) _Float16;
using half4 = __attribute__((ext_vector_type(4))) _Float16;
using half2v = __attribute__((ext_vector_type(2))) _Float16;
using fp16x2 = __attribute__((ext_vector_type(2))) __fp16;
using f32x4 = __attribute__((ext_vector_type(4))) float;
using f32x16 = __attribute__((ext_vector_type(16))) float;

__device__ __forceinline__ f32x4 fz4() { f32x4 v = {0.f, 0.f, 0.f, 0.f}; return v; }

// async global->LDS, 16B per lane; LDS dest = wave-uniform base + lane*16
__device__ __forceinline__ void gload16(const void* g, void* l) {
    __builtin_amdgcn_global_load_lds(
        (const __attribute__((address_space(1))) unsigned int*)g,
        (__attribute__((address_space(3))) unsigned int*)l, 16, 0, 0);
}

__device__ __forceinline__ half2v pk2(float a, float b) {
    fp16x2 t = __builtin_amdgcn_cvt_pkrtz(a, b);
    return __builtin_bit_cast(half2v, t);
}

__device__ __forceinline__ half4 pk4(float a, float b, float c, float d) {
    half2v lo = pk2(a, b);
    half2v hi = pk2(c, d);
    half4 r; r.x = lo.x; r.y = lo.y; r.z = hi.x; r.w = hi.y;
    return r;
}

// XCD-chunked swizzle
__device__ __forceinline__ int xswz(int bid, int n) {
    return (bid & 7) * (n >> 3) + (bid >> 3);
}

// ---------------- fused prep: fp32->fp16 [W|Q|K|V] + mask bitpack ----------------
__global__ __launch_bounds__(256) void prep(const float* __restrict__ wq,
                                            const float* __restrict__ wk,
                                            const float* __restrict__ wv,
                                            const float* __restrict__ wo,
                                            const float* __restrict__ Q,
                                            const float* __restrict__ K,
                                            const float* __restrict__ V,
                                            const int* __restrict__ mask,
                                            _Float16* __restrict__ out,
                                            unsigned int* __restrict__ mbits) {
    const int bid = blockIdx.x;
    if (bid < 2048) {
        int idx = bid * 256 + threadIdx.x;
#pragma unroll
        for (int k = 0; k < 8; ++k) {
            int c = idx + k * 524288;
            const float* src;
            int off;
            if (c < 1048576) {
                int w = c >> 18;
                src = (w == 0) ? wq : (w == 1) ? wk : (w == 2) ? wv : wo;
                off = c & 0x3ffff;
            } else {
                int j = (c >> 20) - 1;
                src = (j == 0) ? Q : (j == 1) ? K : V;
                off = c & 0xfffff;
            }
            float4 v = ((const float4*)src)[off];
            ((half4*)out)[c] = pk4(v.x, v.y, v.z, v.w);
        }
    } else {
        int wid = threadIdx.x >> 6, lane = threadIdx.x & 63;
        int row = (bid - 2048) * 4 + wid;
        const int* mrow = mask + (size_t)row * SEQ;
        unsigned int* orow = mbits + (size_t)row * (SEQ / 32);
        for (int it = 0; it < SEQ / 64; ++it) {
            int v = mrow[it * 64 + lane];
            unsigned long long bal = __ballot(v != 0);
            if (lane == 0)       orow[it * 2]     = (unsigned int)(bal & 0xffffffffull);
            else if (lane == 32) orow[it * 2 + 1] = (unsigned int)(bal >> 32);
        }
    }
}

// ---------------- GEMM body: all-fp16 via global_load_lds (r13 proven form) ----------------
__device__ __forceinline__ void gemm_body(const _Float16* __restrict__ A,
                                          const _Float16* __restrict__ Wh,
                                          const float* __restrict__ bias,
                                          void* __restrict__ outp, int omode, float scale) {
    __shared__ __align__(16) _Float16 Asm[2][64 * 64];
    __shared__ __align__(16) _Float16 Bsm[2][128 * 64];
    const int tid = threadIdx.x;
    const int wg = xswz(blockIdx.x, 512);
    const int bm = wg >> 3, bn = wg & 7;
    const int wid = tid >> 6, lane = tid & 63;
    const int li = lane & 15, g = lane >> 4;
    const int wm = wid >> 1, wn = wid & 1;

    const int brow = wid * 32 + (lane >> 3);
    const char* bsrc = (const char*)(Wh + (size_t)(bn * 128 + brow) * D_MODEL)
                       + (((lane & 7) ^ (brow & 7)) * 16);
    const int bdst = wid * 32 * 128;
    const int arow = wid * 16 + (lane >> 3);
    const char* asrc = (const char*)(A + (size_t)(bm * 64 + arow) * D_MODEL)
                       + (((lane & 7) ^ (arow & 7)) * 16);
    const int adst = wid * 16 * 128;

    f32x4 acc[2][4];
#pragma unroll
    for (int i = 0; i < 2; ++i)
#pragma unroll
        for (int j = 0; j < 4; ++j) acc[i][j] = fz4();

    const int o0 = ((g << 4))      ^ ((li & 7) << 4);
    const int o1 = (64 + (g << 4)) ^ ((li & 7) << 4);
    const int abase = wm * 4096 + li * 128;
    const int bbase = wn * 8192 + li * 128;

    auto stage = [&](int it, int buf) {
        const char* bs = bsrc + it * 128;
        char* bd = (char*)&Bsm[buf][0] + bdst;
        gload16(bs,             bd);
        gload16(bs +  8 * 2048, bd + 1024);
        gload16(bs + 16 * 2048, bd + 2048);
        gload16(bs + 24 * 2048, bd + 3072);
        const char* as = asrc + it * 128;
        char* ad = (char*)&Asm[buf][0] + adst;
        gload16(as,            ad);
        gload16(as + 8 * 2048, ad + 1024);
    };

    stage(0, 0);
    __syncthreads();

    for (int it = 0; it < 16; ++it) {
        const int cur = it & 1;
        if (it + 1 < 16) stage(it + 1, cur ^ 1);
        const char* ab = (const char*)&Asm[cur][0];
        const char* bb = (const char*)&Bsm[cur][0];
#pragma unroll
        for (int s = 0; s < 2; ++s) {
            const int oS = s ? o1 : o0;
            half8 af0 = *(const half8*)(ab + abase + 0    + oS);
            half8 af1 = *(const half8*)(ab + abase + 2048 + oS);
            half8 bf[4];
#pragma unroll
            for (int nt = 0; nt < 4; ++nt)
                bf[nt] = *(const half8*)(bb + bbase + nt * 2048 + oS);
#pragma unroll
            for (int nt = 0; nt < 4; ++nt) {
                acc[0][nt] = __builtin_amdgcn_mfma_f32_16x16x32_f16(af0, bf[nt], acc[0][nt], 0, 0, 0);
                acc[1][nt] = __builtin_amdgcn_mfma_f32_16x16x32_f16(af1, bf[nt], acc[1][nt], 0, 0, 0);
            }
        }
        __syncthreads();
    }

#pragma unroll
    for (int nt = 0; nt < 4; ++nt) {
        int n = bn * 128 + wn * 64 + nt * 16 + li;
        float bv = bias[n];
#pragma unroll
        for (int mt = 0; mt < 2; ++mt) {
            if (omode == 1) {
                int s0 = bm * 64 + wm * 32 + mt * 16 + g * 4;
                int b = (bm * 64) >> 11;
                int h = n >> 6, d = n & 63;
                half4 hv = pk4(acc[mt][nt][0] + bv, acc[mt][nt][1] + bv,
                               acc[mt][nt][2] + bv, acc[mt][nt][3] + bv);
                *(half4*)((_Float16*)outp +
                          ((((size_t)(b * NH + h)) * DKK + d) * SEQ + (s0 & (SEQ - 1)))) = hv;
            } else {
#pragma unroll
                for (int r = 0; r < 4; ++r) {
                    int m = bm * 64 + wm * 32 + mt * 16 + g * 4 + r;
                    float val = (acc[mt][nt][r] + bv) * scale;
                    if (omode == 2) {
                        ((float*)outp)[(size_t)m * D_MODEL + n] = val;
                    } else {
                        int b = m >> 11, s = m & (SEQ - 1);
                        int h = n >> 6, d = n & 63;
                        ((_Float16*)outp)[(((size_t)(b * NH + h)) * SEQ + s) * DKK + d] =
                            (_Float16)val;
                    }
                }
            }
        }
    }
}

struct QkvArgs {
    const float *b0, *b1, *b2;
    _Float16 *o0, *o1, *o2;
};

__global__ __launch_bounds__(256) void gemm_qkv(const _Float16* __restrict__ Ah,
                                                const _Float16* __restrict__ cw,
                                                QkvArgs ga) {
    const int z = blockIdx.y;
    const _Float16* A  = Ah + (size_t)z * (D_MODEL * 4096);
    const float* bi = (z == 0) ? ga.b0 : (z == 1) ? ga.b1 : ga.b2;
    _Float16*    o  = (z == 0) ? ga.o0 : (z == 1) ? ga.o1 : ga.o2;
    gemm_body(A, cw + (size_t)z * D_MODEL * D_MODEL, bi, o,
              (z == 2) ? 1 : 0, (z == 0) ? QSCALE : 1.0f);
}

__global__ __launch_bounds__(256) void gemm_out(const _Float16* __restrict__ A,
                                                const _Float16* __restrict__ cw,
                                                const float* __restrict__ bias,
                                                float* __restrict__ out) {
    gemm_body(A, cw, bias, out, 2, 1.0f);
}

// ---------------- attention: 32x32 MFMA, NO kh-split — wave owns all keys ----------------
// Block = 4 waves x 32 q-rows = 128 q-rows, grid 512 (2 blocks/CU). Each wave walks
// the full 64-key tile as two key-groups (kg=0,1): QK->softmax->pfrag->PV per kg.
// No epilogue combine: every wave normalizes (ones-MFMA lsum) and writes its rows.
// K/V staging cooperative across 4 waves (unchanged from r13), 1 barrier per tile.
__global__ __launch_bounds__(256, 4) void attn_fwd(const _Float16* __restrict__ q,
                                                   const _Float16* __restrict__ kk,
                                                   const _Float16* __restrict__ vt,
                                                   const unsigned int* __restrict__ mb,
                                                   _Float16* __restrict__ aout) {
    __shared__ __align__(16) char smem[32768];
    const int wg = xswz(blockIdx.x, 512);
    const int qblk = wg & 15, bh = wg >> 4;
    const int b = bh >> 4, h = bh & 15;
    const int tid = threadIdx.x, wid = tid >> 6, lane = tid & 63;
    const int l31 = lane & 31, hi = lane >> 5;
    const _Float16* qp = q  + (size_t)bh * SEQ * DKK;
    const _Float16* kp = kk + (size_t)bh * SEQ * DKK;
    const _Float16* vp = vt + (size_t)bh * DKK * SEQ;
    const int qrow = qblk * 128 + wid * 32 + l31;

    half8 qf[4];
#pragma unroll
    for (int s = 0; s < 4; ++s)
        qf[s] = *(const half8*)(qp + (size_t)qrow * DKK + s * 16 + hi * 8);

    half8 ones;
#pragma unroll
    for (int j = 0; j < 8; ++j) ones[j] = (_Float16)1.0f;

    // cooperative staging (identical to r13): wave wid stages rows wid*16 + {0..7,8..15}
    const int srow = wid * 16 + (lane >> 3);
    const int sswz = ((lane & 7) ^ (srow & 7)) * 16;
    const char* ksrc = (const char*)(kp + (size_t)srow * DKK) + sswz;
    const char* vsrc = (const char*)(vp + (size_t)srow * SEQ) + sswz;
    const int sdst = wid * 2048;

    auto stage = [&](int it, int buf) {
        const char* ks = ksrc + (size_t)it * 8192;
        const char* vs = vsrc + (size_t)it * 128;
        char* kd = smem + buf * 8192 + sdst;
        char* vd = smem + 16384 + buf * 8192 + sdst;
        gload16(ks,                       kd);
        gload16(ks + 8 * 128,             kd + 1024);
        gload16(vs,                       vd);
        gload16(vs + 8 * (size_t)SEQ * 2, vd + 1024);
    };

    f32x16 O0, O1, Ol;
#pragma unroll
    for (int j = 0; j < 16; ++j) { O0[j] = 0.f; O1[j] = 0.f; Ol[j] = 0.f; }

    const unsigned int* mrow = mb + (size_t)(b * SEQ + qrow) * (SEQ / 32);

    const int v0row = l31;
    const int v1row = 32 + l31;

    stage(0, 0);
    __syncthreads();

    for (int it = 0; it < SEQ / 64; ++it) {
        const int cur = it & 1;
        if (it + 1 < SEQ / 64) stage(it + 1, cur ^ 1);
        const char* kb_ = smem + cur * 8192;
        const char* vb_ = smem + 16384 + cur * 8192;

#pragma unroll
        for (int kg = 0; kg < 2; ++kg) {
            const unsigned mw = mrow[it * 2 + kg] >> (hi * 4);
            const int krow = kg * 32 + l31;
            const int kbase = krow * 128;
            const int krx = (krow & 7);

            // S^T = K·Q^T over this key-group
            f32x16 st;
#pragma unroll
            for (int j = 0; j < 16; ++j) st[j] = 0.f;
            __builtin_amdgcn_s_setprio(1);
#pragma unroll
            for (int s = 0; s < 4; ++s) {
                const int c = s * 2 + hi;
                half8 kf = *(const half8*)(kb_ + kbase + ((c ^ krx) << 4));
                st = __builtin_amdgcn_mfma_f32_32x32x16_f16(kf, qf[s], st, 0, 0, 0);
            }
            __builtin_amdgcn_s_setprio(0);

            // softmax (fixed max 0) + mask; pack to fp16 words
            unsigned w[8];
#pragma unroll
            for (int rq = 0; rq < 4; ++rq) {
                float e0 = __builtin_amdgcn_exp2f(st[rq * 4 + 0]);
                float e1 = __builtin_amdgcn_exp2f(st[rq * 4 + 1]);
                float e2 = __builtin_amdgcn_exp2f(st[rq * 4 + 2]);
                float e3 = __builtin_amdgcn_exp2f(st[rq * 4 + 3]);
                float p0 = ((mw >> (8 * rq + 0)) & 1u) ? e0 : 1.0f;
                float p1 = ((mw >> (8 * rq + 1)) & 1u) ? e1 : 1.0f;
                float p2 = ((mw >> (8 * rq + 2)) & 1u) ? e2 : 1.0f;
                float p3 = ((mw >> (8 * rq + 3)) & 1u) ? e3 : 1.0f;
                w[2 * rq]     = __builtin_bit_cast(unsigned, pk2(p0, p1));
                w[2 * rq + 1] = __builtin_bit_cast(unsigned, pk2(p2, p3));
            }

            // rebuild P^T B-fragments in registers (half-exchange across lane 32)
            half8 pfrag[2];
#pragma unroll
            for (int s2 = 0; s2 < 2; ++s2) {
                unsigned a0 = w[s2 * 4 + 0], a1 = w[s2 * 4 + 1];
                unsigned a2 = w[s2 * 4 + 2], a3 = w[s2 * 4 + 3];
                unsigned t0 = (unsigned)__shfl_xor((int)(hi ? a0 : a2), 32);
                unsigned t1 = (unsigned)__shfl_xor((int)(hi ? a1 : a3), 32);
                uint4 f;
                f.x = hi ? t0 : a0;
                f.y = hi ? t1 : a1;
                f.z = hi ? a2 : t0;
                f.w = hi ? a3 : t1;
                pfrag[s2] = __builtin_bit_cast(half8, f);
            }

            // O^T += V^T·P^T over this key-group; lsum via ones-MFMA
            __builtin_amdgcn_s_setprio(1);
#pragma unroll
            for (int s2 = 0; s2 < 2; ++s2) {
                const int c = kg * 4 + s2 * 2 + hi;
                half8 vf0 = *(const half8*)(vb_ + v0row * 128 + ((c ^ (v0row & 7)) << 4));
                half8 vf1 = *(const half8*)(vb_ + v1row * 128 + ((c ^ (v1row & 7)) << 4));
                Ol = __builtin_amdgcn_mfma_f32_32x32x16_f16(ones, pfrag[s2], Ol, 0, 0, 0);
                O0 = __builtin_amdgcn_mfma_f32_32x32x16_f16(vf0, pfrag[s2], O0, 0, 0, 0);
                O1 = __builtin_amdgcn_mfma_f32_32x32x16_f16(vf1, pfrag[s2], O1, 0, 0, 0);
            }
            __builtin_amdgcn_s_setprio(0);
        }
        __syncthreads();
    }

    // ---- epilogue: no combine; every lane holds full lsum(q=l31) in Ol[0] ----
    float inv = 1.0f / Ol[0];
    _Float16* orow = aout + ((size_t)(b * SEQ + qrow)) * D_MODEL + h * DKK + hi * 4;
#pragma unroll
    for (int rq = 0; rq < 4; ++rq) {
        *(half4*)(orow + 8 * rq) =
            pk4(O0[rq * 4 + 0] * inv, O0[rq * 4 + 1] * inv,
                O0[rq * 4 + 2] * inv, O0[rq * 4 + 3] * inv);
        *(half4*)(orow + 32 + 8 * rq) =
            pk4(O1[rq * 4 + 0] * inv, O1[rq * 4 + 1] * inv,
                O1[rq * 4 + 2] * inv, O1[rq * 4 + 3] * inv);
    }
}

extern "C" void kernel_launch(void* const* d_in, const int* in_sizes, int n_in,
                              void* d_out, int out_size, void* d_ws, size_t ws_size,
                              hipStream_t stream) {
    const float* Q    = (const float*)d_in[0];
    const float* Kin  = (const float*)d_in[1];
    const float* Vin  = (const float*)d_in[2];
    const int*   mask = (const int*)d_in[3];
    const float* WQw = (const float*)d_in[4];
    const float* WQb = (const float*)d_in[5];
    const float* WKw = (const float*)d_in[6];
    const float* WKb = (const float*)d_in[7];
    const float* WVw = (const float*)d_in[8];
    const float* WVb = (const float*)d_in[9];
    const float* WOw = (const float*)d_in[10];
    const float* WOb = (const float*)d_in[11];

    char* w = (char*)d_ws;
    const size_t MB = 1ull << 20;
    // ws layout (57 MB):
    //  [0,8)   cw    fp16 weights WQ|WK|WV|WO
    //  [8,32)  Ah    fp16 Q|K|V inputs (Q region [8,16) reused as ab after gemm_qkv)
    //  [32,40) qb  [40,48) kbf  [48,56) vtb
    //  [56,57) mbits
    _Float16* cw  = (_Float16*)(w);
    _Float16* Ah  = (_Float16*)(w + 8 * MB);
    _Float16* ab  = (_Float16*)(w + 8 * MB);
    _Float16* qb  = (_Float16*)(w + 32 * MB);
    _Float16* kbf = (_Float16*)(w + 40 * MB);
    _Float16* vtb = (_Float16*)(w + 48 * MB);
    unsigned int* mbits = (unsigned int*)(w + 56 * MB);

    prep<<<dim3(3072), dim3(256), 0, stream>>>(WQw, WKw, WVw, WOw, Q, Kin, Vin, mask,
                                               cw, mbits);

    QkvArgs ga;
    ga.b0 = WQb; ga.b1 = WKb; ga.b2 = WVb;
    ga.o0 = qb;  ga.o1 = kbf; ga.o2 = vtb;
    gemm_qkv<<<dim3(512, 3), dim3(256), 0, stream>>>(Ah, cw, ga);

    attn_fwd<<<dim3(512), dim3(256), 0, stream>>>(qb, kbf, vtb, mbits, ab);

    gemm_out<<<dim3(512), dim3(256), 0, stream>>>(ab, cw + 3ull * D_MODEL * D_MODEL, WOb,
                                                  (float*)d_out);
}